// Round 4
// baseline (1099.027 us; speedup 1.0000x reference)
//
#include <hip/hip_runtime.h>
#include <hip/hip_bf16.h>

// ---- problem constants ----
#define B_     4
#define N_     8192
#define MD_    512
#define OC_    536        // HEADS*(FEAT+3)
#define HEADS_ 8
#define FEAT_  64
#define NC_    32768      // 32^3 cells
#define ZTOT_  67108864ll // B*HEADS*FEAT*NC
#define NPTS_  262144     // B*HEADS*N
#define NKEYS_ 786432.0f  // B*HEADS*3*N

// ============================================================
// Kernel 1: GEMM  kv[b][o][n] = sum_m W[o][m] * X[b][m][n]
// + fused per-channel partial sums for BN stats (atomic f32)
// ============================================================
__global__ __launch_bounds__(256) void gemm_kernel(const float* __restrict__ W,
                                                   const float* __restrict__ X,
                                                   float* __restrict__ KV,
                                                   float* __restrict__ ssum,
                                                   float* __restrict__ s2sum) {
  const int n0 = blockIdx.x * 256;
  const int m0 = blockIdx.y * 64;
  const int b  = blockIdx.z;
  __shared__ float Wt[32][68];    // Wt[k][m]
  __shared__ float In[32][260];   // In[k][n]
  const int t  = threadIdx.x;
  const int tx = t & 31;
  const int ty = t >> 5;
  float acc[8][8];
#pragma unroll
  for (int r = 0; r < 8; ++r)
#pragma unroll
    for (int c = 0; c < 8; ++c) acc[r][c] = 0.f;

  const float* Xb = X + (size_t)b * MD_ * N_;
  for (int k0 = 0; k0 < MD_; k0 += 32) {
#pragma unroll
    for (int i = 0; i < 8; ++i) {
      int idx = t + i * 256;
      int m = idx >> 5, k = idx & 31;
      int mm = m0 + m;
      Wt[k][m] = (mm < OC_) ? W[(size_t)mm * MD_ + (k0 + k)] : 0.f;
    }
#pragma unroll
    for (int i = 0; i < 8; ++i) {
      int slot = t + i * 256;
      int k = slot >> 6, n4 = slot & 63;
      float4 v = *(const float4*)(Xb + (size_t)(k0 + k) * N_ + n0 + n4 * 4);
      *(float4*)&In[k][n4 * 4] = v;
    }
    __syncthreads();
#pragma unroll
    for (int k = 0; k < 32; ++k) {
      float a[8], bb[8];
      *(float4*)&a[0]  = *(const float4*)&Wt[k][ty * 8];
      *(float4*)&a[4]  = *(const float4*)&Wt[k][ty * 8 + 4];
      *(float4*)&bb[0] = *(const float4*)&In[k][tx * 4];
      *(float4*)&bb[4] = *(const float4*)&In[k][128 + tx * 4];
#pragma unroll
      for (int r = 0; r < 8; ++r)
#pragma unroll
        for (int c = 0; c < 8; ++c)
          acc[r][c] = fmaf(a[r], bb[c], acc[r][c]);
    }
    __syncthreads();
  }
#pragma unroll
  for (int r = 0; r < 8; ++r) {
    int mm = m0 + ty * 8 + r;
    float s = 0.f, s2 = 0.f;
#pragma unroll
    for (int c = 0; c < 8; ++c) { float v = acc[r][c]; s += v; s2 = fmaf(v, v, s2); }
#pragma unroll
    for (int off = 16; off; off >>= 1) {
      s  += __shfl_down(s, off, 32);
      s2 += __shfl_down(s2, off, 32);
    }
    if (mm < OC_) {
      float* dst = KV + ((size_t)b * OC_ + mm) * N_ + n0;
      *(float4*)(dst + tx * 4)       = *(float4*)&acc[r][0];
      *(float4*)(dst + 128 + tx * 4) = *(float4*)&acc[r][4];
      if (tx == 0) { atomicAdd(&ssum[mm], s); atomicAdd(&s2sum[mm], s2); }
    }
  }
}

// ============================================================
// Kernel 2: finalize BN -> scale/shift per channel
// ============================================================
__global__ __launch_bounds__(256) void bnfin_kernel(const float* __restrict__ ssum,
                                                    const float* __restrict__ s2sum,
                                                    const float* __restrict__ kg,
                                                    const float* __restrict__ kb,
                                                    const float* __restrict__ vg,
                                                    const float* __restrict__ vb,
                                                    float* __restrict__ scale,
                                                    float* __restrict__ shift) {
  const int o = blockIdx.x * 256 + threadIdx.x;
  if (o >= OC_) return;
  const float inv = 1.0f / (B_ * N_);
  float mu  = ssum[o] * inv;
  float var = s2sum[o] * inv - mu * mu;
  float g, be;
  if (o < 24) { g = kg[o]; be = kb[o]; }
  else        { g = vg[o - 24]; be = vb[o - 24]; }
  float sc = g * rsqrtf(var + 1e-5f);
  scale[o] = sc;
  shift[o] = be - mu * sc;
}

// ============================================================
// Kernel 3: per-point keys -> {r0,r1,r2, cell} (16B/point)
//           + keys mean/var partials
// ============================================================
__global__ __launch_bounds__(256) void passk_kernel(const float* __restrict__ KV,
                                                    const float* __restrict__ orig,
                                                    const float* __restrict__ proj,
                                                    const float* __restrict__ scale,
                                                    const float* __restrict__ shift,
                                                    float4* __restrict__ cellr,
                                                    float* __restrict__ kacc) {
  const int p = blockIdx.x * 256 + threadIdx.x;
  const int bh = p >> 13, n = p & (N_ - 1);
  const int b = bh >> 3, h = bh & 7;
  const float* KVb = KV + (size_t)b * OC_ * N_;
  float pt[3];
#pragma unroll
  for (int k = 0; k < 3; ++k) {
    int ch = h * 3 + k;
    float kr = fmaf(KVb[(size_t)ch * N_ + n], scale[ch], shift[ch]);
    pt[k] = orig[((size_t)b * 3 + k) * N_ + n] + kr;
  }
  float ksum = 0.f, ksq = 0.f;
  int cell = 0;
  float rr[3];
#pragma unroll
  for (int d = 0; d < 3; ++d) {
    const float* pr = proj + (h * 3 + d) * 3;
    float key = pr[0] * pt[0] + pr[1] * pt[1] + pr[2] * pt[2];
    ksum += key; ksq += key * key;
    float lat = tanhf(key);
    float c = (lat + 1.0f) * 15.5f;
    float fl = floorf(c);
    fl = fminf(fmaxf(fl, 0.0f), 30.0f);
    rr[d] = c - fl;
    cell += (int)fl * ((d == 0) ? 1024 : (d == 1) ? 32 : 1);
  }
  cellr[p] = make_float4(rr[0], rr[1], rr[2], __int_as_float(cell));
#pragma unroll
  for (int off = 32; off; off >>= 1) {
    ksum += __shfl_down(ksum, off);
    ksq  += __shfl_down(ksq, off);
  }
  if ((threadIdx.x & 63) == 0) {
    atomicAdd(&kacc[0], ksum);
    atomicAdd(&kacc[1], ksq);
  }
}

// ============================================================
// Kernel 4: dense accumulate — block = (bh, feat), FULL 32^3
// grid in 128 KiB LDS. Streams 8192 points with 4-deep ILP,
// 8 unconditional LDS atomics each; coalesced z write + occ.
// ============================================================
__global__ __launch_bounds__(512, 1) void accum_kernel(const float* __restrict__ KV,
                                                       const float* __restrict__ scale,
                                                       const float* __restrict__ shift,
                                                       const float4* __restrict__ cellr,
                                                       float* __restrict__ zout,
                                                       unsigned int* __restrict__ occ) {
  const int blk = blockIdx.x;       // bh*64 + f
  const int f   = blk & 63;
  const int bh  = blk >> 6;
  const int b = bh >> 3, h = bh & 7;
  __shared__ float tile[NC_];       // 128 KiB
  const int t = threadIdx.x;
#pragma unroll
  for (int i = 0; i < 16; ++i)
    ((float4*)tile)[t + i * 512] = make_float4(0.f, 0.f, 0.f, 0.f);
  __syncthreads();

  const int ch = 24 + h * 64 + f;
  const float sc = scale[ch], sh = shift[ch];
  const float* kvrow = KV + ((size_t)b * OC_ + ch) * N_;
  const float4* cr = cellr + (size_t)bh * N_;

  for (int n0 = 0; n0 < N_; n0 += 2048) {
    float4 m0 = cr[n0 + t];
    float4 m1 = cr[n0 + t + 512];
    float4 m2 = cr[n0 + t + 1024];
    float4 m3 = cr[n0 + t + 1536];
    float k0 = kvrow[n0 + t];
    float k1 = kvrow[n0 + t + 512];
    float k2 = kvrow[n0 + t + 1024];
    float k3 = kvrow[n0 + t + 1536];
#define POINT(M, K)                                                  \
    {                                                                \
      int cell = __float_as_int((M).w);                              \
      float v  = fmaf((K), sc, sh);                                  \
      float r0 = (M).x, r1 = (M).y, r2 = (M).z;                      \
      float va = v * (1.f - r0), vb = v * r0;                        \
      float c00 = (1.f - r1) * (1.f - r2), c01 = (1.f - r1) * r2;    \
      float c10 = r1 * (1.f - r2),         c11 = r1 * r2;            \
      atomicAdd(&tile[cell],        va * c00);                       \
      atomicAdd(&tile[cell + 1],    va * c01);                       \
      atomicAdd(&tile[cell + 32],   va * c10);                       \
      atomicAdd(&tile[cell + 33],   va * c11);                       \
      atomicAdd(&tile[cell + 1024], vb * c00);                       \
      atomicAdd(&tile[cell + 1025], vb * c01);                       \
      atomicAdd(&tile[cell + 1056], vb * c10);                       \
      atomicAdd(&tile[cell + 1057], vb * c11);                       \
    }
    POINT(m0, k0) POINT(m1, k1) POINT(m2, k2) POINT(m3, k3)
#undef POINT
  }
  __syncthreads();

  unsigned int cnt = 0;
  float* dst = zout + (size_t)blk * NC_;
#pragma unroll
  for (int i = 0; i < 16; ++i) {
    float4 v = ((const float4*)tile)[t + i * 512];
    cnt += (fabsf(v.x) > 1e-9f) ? 1u : 0u;
    cnt += (fabsf(v.y) > 1e-9f) ? 1u : 0u;
    cnt += (fabsf(v.z) > 1e-9f) ? 1u : 0u;
    cnt += (fabsf(v.w) > 1e-9f) ? 1u : 0u;
    ((float4*)dst)[t + i * 512] = v;
  }
#pragma unroll
  for (int off = 32; off; off >>= 1) cnt += __shfl_down(cnt, off);
  __shared__ unsigned int wc[8];
  if ((t & 63) == 0) wc[t >> 6] = cnt;
  __syncthreads();
  if (t == 0) {
    unsigned int s = 0;
#pragma unroll
    for (int i = 0; i < 8; ++i) s += wc[i];
    atomicAdd(occ, s);
  }
}

// ---- fallback path (small ws): direct final-layout splat ----
__global__ __launch_bounds__(256) void splat_final_kernel(const float* __restrict__ KV,
                                                          const float* __restrict__ orig,
                                                          const float* __restrict__ proj,
                                                          const float* __restrict__ scale,
                                                          const float* __restrict__ shift,
                                                          float* __restrict__ Z,
                                                          float* __restrict__ kacc) {
  const int bh = blockIdx.x >> 7;
  const int n0 = (blockIdx.x & 127) << 6;
  const int b = bh >> 3, h = bh & 7;
  __shared__ float vals[64][65];
  __shared__ int   cellS[64];
  __shared__ float rS[64][4];
  const int t = threadIdx.x;
  const float* KVb = KV + (size_t)b * OC_ * N_;
  const int ch0 = 24 + h * 64;
#pragma unroll
  for (int i = 0; i < 16; ++i) {
    int idx = t + i * 256;
    int f = idx >> 6, p = idx & 63;
    int ch = ch0 + f;
    vals[f][p] = fmaf(KVb[(size_t)ch * N_ + n0 + p], scale[ch], shift[ch]);
  }
  if (t < 64) {
    const int n = n0 + t;
    float pt[3];
#pragma unroll
    for (int k = 0; k < 3; ++k) {
      int ch = h * 3 + k;
      float kr = fmaf(KVb[(size_t)ch * N_ + n], scale[ch], shift[ch]);
      pt[k] = orig[((size_t)b * 3 + k) * N_ + n] + kr;
    }
    float ksum = 0.f, ksq = 0.f;
    int cell = 0;
    float rr[3];
#pragma unroll
    for (int d = 0; d < 3; ++d) {
      const float* pr = proj + (h * 3 + d) * 3;
      float key = pr[0] * pt[0] + pr[1] * pt[1] + pr[2] * pt[2];
      ksum += key; ksq += key * key;
      float lat = tanhf(key);
      float c = (lat + 1.0f) * 15.5f;
      float fl = floorf(c);
      fl = fminf(fmaxf(fl, 0.0f), 30.0f);
      rr[d] = c - fl;
      cell += (int)fl * ((d == 0) ? 1024 : (d == 1) ? 32 : 1);
    }
    cellS[t] = cell;
    rS[t][0] = rr[0]; rS[t][1] = rr[1]; rS[t][2] = rr[2];
#pragma unroll
    for (int off = 32; off; off >>= 1) {
      ksum += __shfl_down(ksum, off);
      ksq  += __shfl_down(ksq, off);
    }
    if (t == 0) { atomicAdd(&kacc[0], ksum); atomicAdd(&kacc[1], ksq); }
  }
  __syncthreads();
  const int w = t >> 6, l = t & 63;
  for (int pi = 0; pi < 16; ++pi) {
    int p = w * 16 + pi;
    int cell = cellS[p];
    float r0 = rS[p][0], r1 = rS[p][1], r2 = rS[p][2];
    float u0 = 1.f - r0, u1 = 1.f - r1, u2 = 1.f - r2;
    float v = vals[l][p];
#pragma unroll
    for (int c = 0; c < 8; ++c) {
      float wt = ((c & 4) ? r0 : u0) * ((c & 2) ? r1 : u1) * ((c & 1) ? r2 : u2);
      int cc = cell + ((c & 4) ? 1024 : 0) + ((c & 2) ? 32 : 0) + (c & 1);
      atomicAdd(Z + (size_t)(bh * 64 + l) * NC_ + cc, v * wt);
    }
  }
}

__global__ __launch_bounds__(256) void count_kernel(const float* __restrict__ Z,
                                                    unsigned int* __restrict__ occ) {
  unsigned int cnt = 0;
  for (long long i = (long long)blockIdx.x * blockDim.x + threadIdx.x; i < ZTOT_;
       i += (long long)gridDim.x * blockDim.x)
    cnt += (fabsf(Z[i]) > 1e-9f) ? 1u : 0u;
#pragma unroll
  for (int off = 32; off; off >>= 1) cnt += __shfl_down(cnt, off);
  __shared__ unsigned int wc[4];
  const int t = threadIdx.x;
  if ((t & 63) == 0) wc[t >> 6] = cnt;
  __syncthreads();
  if (t == 0) atomicAdd(occ, wc[0] + wc[1] + wc[2] + wc[3]);
}

__global__ void finalize_kernel(const unsigned int* __restrict__ occ,
                                const float* __restrict__ kacc,
                                float* __restrict__ tail) {
  float mean = kacc[0] / NKEYS_;
  tail[0] = (float)(*occ) * (1.0f / 2048.0f);
  tail[1] = mean;
  tail[2] = kacc[1] / NKEYS_ - mean * mean;
}

// ============================================================
extern "C" void kernel_launch(void* const* d_in, const int* in_sizes, int n_in,
                              void* d_out, int out_size, void* d_ws, size_t ws_size,
                              hipStream_t stream) {
  const float* X    = (const float*)d_in[0];
  const float* orig = (const float*)d_in[1];
  const float* W    = (const float*)d_in[2];
  const float* kg   = (const float*)d_in[3];
  const float* kb   = (const float*)d_in[4];
  const float* vg   = (const float*)d_in[5];
  const float* vb   = (const float*)d_in[6];
  const float* proj = (const float*)d_in[7];
  float* out = (float*)d_out;

  // ws stats page (16 KB)
  float* P = (float*)d_ws;
  float* ssum  = P;                         // [536]
  float* s2sum = P + 544;                   // [536]
  float* kacc  = P + 1088;                  // [2]
  unsigned int* occ = (unsigned int*)(P + 1090);
  float* scale = P + 1152;                  // [536]
  float* shift = P + 1696;                  // [536]
  char* wsb = (char*)d_ws;

  const size_t need = (size_t)82 << 20;
  if (ws_size >= need) {
    float4* cellr = (float4*)(wsb + 65536);               // 4 MB @64KB
    float*  kv    = (float*)(wsb + ((size_t)8 << 20));    // 70.3 MB @8MB

    // zero ssum/s2sum/kacc/occ
    hipMemsetAsync(P, 0, 4368, stream);

    gemm_kernel<<<dim3(N_ / 256, 9, B_), 256, 0, stream>>>(W, X, kv, ssum, s2sum);
    bnfin_kernel<<<3, 256, 0, stream>>>(ssum, s2sum, kg, kb, vg, vb, scale, shift);
    passk_kernel<<<NPTS_ / 256, 256, 0, stream>>>(kv, orig, proj, scale, shift,
                                                  cellr, kacc);
    accum_kernel<<<2048, 512, 0, stream>>>(kv, scale, shift, cellr, out, occ);
    finalize_kernel<<<1, 1, 0, stream>>>(occ, kacc, out + ZTOT_);
  } else {
    // fallback: kv in ws, splat straight into d_out final layout
    float* kv = (float*)(wsb + 16384);
    hipMemsetAsync(P, 0, 4368, stream);
    hipMemsetAsync(out, 0, (size_t)ZTOT_ * 4, stream);
    gemm_kernel<<<dim3(N_ / 256, 9, B_), 256, 0, stream>>>(W, X, kv, ssum, s2sum);
    bnfin_kernel<<<3, 256, 0, stream>>>(ssum, s2sum, kg, kb, vg, vb, scale, shift);
    splat_final_kernel<<<B_ * HEADS_ * (N_ / 64), 256, 0, stream>>>(
        kv, orig, proj, scale, shift, out, kacc);
    count_kernel<<<2048, 256, 0, stream>>>(out, occ);
    finalize_kernel<<<1, 1, 0, stream>>>(occ, kacc, out + ZTOT_);
  }
}

// Round 5
// 873.786 us; speedup vs baseline: 1.2578x; 1.2578x over previous
//
#include <hip/hip_runtime.h>
#include <hip/hip_bf16.h>

// ---- problem constants ----
#define B_     4
#define N_     8192
#define MD_    512
#define OC_    536        // HEADS*(FEAT+3)
#define HEADS_ 8
#define FEAT_  64
#define NC_    32768      // 32^3 cells
#define ZTOT_  67108864ll // B*HEADS*FEAT*NC
#define NPTS_  262144     // B*HEADS*N
#define NKEYS_ 786432.0f  // B*HEADS*3*N

// ============================================================
// Kernel 1: GEMM  kv[b][o][n] = sum_m W[o][m] * X[b][m][n]
// + fused per-channel partial sums for BN stats (atomic f32)
// ============================================================
__global__ __launch_bounds__(256) void gemm_kernel(const float* __restrict__ W,
                                                   const float* __restrict__ X,
                                                   float* __restrict__ KV,
                                                   float* __restrict__ ssum,
                                                   float* __restrict__ s2sum) {
  const int n0 = blockIdx.x * 256;
  const int m0 = blockIdx.y * 64;
  const int b  = blockIdx.z;
  __shared__ float Wt[32][68];    // Wt[k][m]
  __shared__ float In[32][260];   // In[k][n]
  const int t  = threadIdx.x;
  const int tx = t & 31;
  const int ty = t >> 5;
  float acc[8][8];
#pragma unroll
  for (int r = 0; r < 8; ++r)
#pragma unroll
    for (int c = 0; c < 8; ++c) acc[r][c] = 0.f;

  const float* Xb = X + (size_t)b * MD_ * N_;
  for (int k0 = 0; k0 < MD_; k0 += 32) {
#pragma unroll
    for (int i = 0; i < 8; ++i) {
      int idx = t + i * 256;
      int m = idx >> 5, k = idx & 31;
      int mm = m0 + m;
      Wt[k][m] = (mm < OC_) ? W[(size_t)mm * MD_ + (k0 + k)] : 0.f;
    }
#pragma unroll
    for (int i = 0; i < 8; ++i) {
      int slot = t + i * 256;
      int k = slot >> 6, n4 = slot & 63;
      float4 v = *(const float4*)(Xb + (size_t)(k0 + k) * N_ + n0 + n4 * 4);
      *(float4*)&In[k][n4 * 4] = v;
    }
    __syncthreads();
#pragma unroll
    for (int k = 0; k < 32; ++k) {
      float a[8], bb[8];
      *(float4*)&a[0]  = *(const float4*)&Wt[k][ty * 8];
      *(float4*)&a[4]  = *(const float4*)&Wt[k][ty * 8 + 4];
      *(float4*)&bb[0] = *(const float4*)&In[k][tx * 4];
      *(float4*)&bb[4] = *(const float4*)&In[k][128 + tx * 4];
#pragma unroll
      for (int r = 0; r < 8; ++r)
#pragma unroll
        for (int c = 0; c < 8; ++c)
          acc[r][c] = fmaf(a[r], bb[c], acc[r][c]);
    }
    __syncthreads();
  }
#pragma unroll
  for (int r = 0; r < 8; ++r) {
    int mm = m0 + ty * 8 + r;
    float s = 0.f, s2 = 0.f;
#pragma unroll
    for (int c = 0; c < 8; ++c) { float v = acc[r][c]; s += v; s2 = fmaf(v, v, s2); }
#pragma unroll
    for (int off = 16; off; off >>= 1) {
      s  += __shfl_down(s, off, 32);
      s2 += __shfl_down(s2, off, 32);
    }
    if (mm < OC_) {
      float* dst = KV + ((size_t)b * OC_ + mm) * N_ + n0;
      *(float4*)(dst + tx * 4)       = *(float4*)&acc[r][0];
      *(float4*)(dst + 128 + tx * 4) = *(float4*)&acc[r][4];
      if (tx == 0) { atomicAdd(&ssum[mm], s); atomicAdd(&s2sum[mm], s2); }
    }
  }
}

// ============================================================
// Kernel 2: finalize BN -> scale/shift per channel
// ============================================================
__global__ __launch_bounds__(256) void bnfin_kernel(const float* __restrict__ ssum,
                                                    const float* __restrict__ s2sum,
                                                    const float* __restrict__ kg,
                                                    const float* __restrict__ kb,
                                                    const float* __restrict__ vg,
                                                    const float* __restrict__ vb,
                                                    float* __restrict__ scale,
                                                    float* __restrict__ shift) {
  const int o = blockIdx.x * 256 + threadIdx.x;
  if (o >= OC_) return;
  const float inv = 1.0f / (B_ * N_);
  float mu  = ssum[o] * inv;
  float var = s2sum[o] * inv - mu * mu;
  float g, be;
  if (o < 24) { g = kg[o]; be = kb[o]; }
  else        { g = vg[o - 24]; be = vb[o - 24]; }
  float sc = g * rsqrtf(var + 1e-5f);
  scale[o] = sc;
  shift[o] = be - mu * sc;
}

// ============================================================
// Kernel 3: per-point keys -> {r0,r1,r2, cell} (16B/point)
//           + keys mean/var partials
// ============================================================
__global__ __launch_bounds__(256) void passk_kernel(const float* __restrict__ KV,
                                                    const float* __restrict__ orig,
                                                    const float* __restrict__ proj,
                                                    const float* __restrict__ scale,
                                                    const float* __restrict__ shift,
                                                    float4* __restrict__ cellr,
                                                    float* __restrict__ kacc) {
  const int p = blockIdx.x * 256 + threadIdx.x;
  const int bh = p >> 13, n = p & (N_ - 1);
  const int b = bh >> 3, h = bh & 7;
  const float* KVb = KV + (size_t)b * OC_ * N_;
  float pt[3];
#pragma unroll
  for (int k = 0; k < 3; ++k) {
    int ch = h * 3 + k;
    float kr = fmaf(KVb[(size_t)ch * N_ + n], scale[ch], shift[ch]);
    pt[k] = orig[((size_t)b * 3 + k) * N_ + n] + kr;
  }
  float ksum = 0.f, ksq = 0.f;
  int cell = 0;
  float rr[3];
#pragma unroll
  for (int d = 0; d < 3; ++d) {
    const float* pr = proj + (h * 3 + d) * 3;
    float key = pr[0] * pt[0] + pr[1] * pt[1] + pr[2] * pt[2];
    ksum += key; ksq += key * key;
    float lat = tanhf(key);
    float c = (lat + 1.0f) * 15.5f;
    float fl = floorf(c);
    fl = fminf(fmaxf(fl, 0.0f), 30.0f);
    rr[d] = c - fl;
    cell += (int)fl * ((d == 0) ? 1024 : (d == 1) ? 32 : 1);
  }
  cellr[p] = make_float4(rr[0], rr[1], rr[2], __int_as_float(cell));
#pragma unroll
  for (int off = 32; off; off >>= 1) {
    ksum += __shfl_down(ksum, off);
    ksq  += __shfl_down(ksq, off);
  }
  if ((threadIdx.x & 63) == 0) {
    atomicAdd(&kacc[0], ksum);
    atomicAdd(&kacc[1], ksq);
  }
}

// ============================================================
// Kernel 3b: per-bh counting sort of points by cell.
// LDS histogram = 32768 bins (128 KiB). Bank-staggered chunk
// scans; grouping (not strict ordering) is all accum needs,
// but chunk order here IS ascending-cell within rotation.
// Output: sorted[bh][i] = {r0,r1,r2, bitcast(cell | n<<15)}
// ============================================================
__global__ __launch_bounds__(1024, 1) void sortk_kernel(const float4* __restrict__ cellr,
                                                        float4* __restrict__ sorted) {
  const int bh = blockIdx.x;
  __shared__ int hist[NC_];      // 128 KiB
  __shared__ int wsum[16];
  const int t = threadIdx.x;
  for (int i = t; i < NC_; i += 1024) hist[i] = 0;
  __syncthreads();
  const float4* cr = cellr + (size_t)bh * N_;
#pragma unroll
  for (int i = 0; i < 8; ++i) {
    int cell = __float_as_int(cr[t + i * 1024].w);
    atomicAdd(&hist[cell], 1);
  }
  __syncthreads();
  // thread t owns bins [t*32, t*32+32), visited in bank-staggered order
  const int base = t * 32;
  int s = 0;
#pragma unroll
  for (int j = 0; j < 32; ++j) s += hist[base + ((j + t) & 31)];
  const int lane = t & 63, wv = t >> 6;
  int sc = s;
#pragma unroll
  for (int off = 1; off < 64; off <<= 1) {
    int x = __shfl_up(sc, off);
    if (lane >= off) sc += x;
  }
  if (lane == 63) wsum[wv] = sc;
  __syncthreads();
  if (t < 16) {
    int x = wsum[t];
    int sc2 = x;
#pragma unroll
    for (int off = 1; off < 16; off <<= 1) {
      int y = __shfl_up(sc2, off);
      if (t >= off) sc2 += y;
    }
    wsum[t] = sc2 - x;    // exclusive wave offset
  }
  __syncthreads();
  int run = sc - s + wsum[wv];   // exclusive start of this thread's chunk
#pragma unroll
  for (int j = 0; j < 32; ++j) {
    int idx = base + ((j + t) & 31);
    int v = hist[idx];
    hist[idx] = run;
    run += v;
  }
  __syncthreads();
  float4* dst = sorted + (size_t)bh * N_;
#pragma unroll
  for (int i = 0; i < 8; ++i) {
    int n = t + i * 1024;
    float4 m = cr[n];
    int cell = __float_as_int(m.w);
    int pos = atomicAdd(&hist[cell], 1);
    m.w = __int_as_float(cell | (n << 15));
    dst[pos] = m;
  }
}

// ============================================================
// Kernel 4: dense accumulate — block = (bh, feat), full 32^3
// grid in 128 KiB LDS. Waves read 64 consecutive SORTED
// entries; duplicates merged via segmented shfl-scan (VALU);
// only segment tails touch the LDS atomic pipe.
// ============================================================
__global__ __launch_bounds__(512, 1) void accum_kernel(const float* __restrict__ KV,
                                                       const float* __restrict__ scale,
                                                       const float* __restrict__ shift,
                                                       const float4* __restrict__ sorted,
                                                       float* __restrict__ zout,
                                                       unsigned int* __restrict__ occ) {
  const int blk = blockIdx.x;       // bh*64 + f
  const int f   = blk & 63;
  const int bh  = blk >> 6;
  const int b = bh >> 3, h = bh & 7;
  __shared__ float tile[NC_];       // 128 KiB
  const int t = threadIdx.x;
#pragma unroll
  for (int i = 0; i < 16; ++i)
    ((float4*)tile)[t + i * 512] = make_float4(0.f, 0.f, 0.f, 0.f);
  __syncthreads();

  const int ch = 24 + h * 64 + f;
  const float sc = scale[ch], sh = shift[ch];
  const float* kvrow = KV + ((size_t)b * OC_ + ch) * N_;
  const float4* sp = sorted + (size_t)bh * N_;
  const int lane = t & 63;

  for (int i = 0; i < 16; ++i) {
    float4 m = sp[i * 512 + t];          // wave reads 64 consecutive entries
    int packed = __float_as_int(m.w);
    int cell = packed & 32767;
    int n    = packed >> 15;
    float v  = fmaf(kvrow[n], sc, sh);
    float r0 = m.x, r1 = m.y, r2 = m.z;
    float va = v * (1.f - r0), vb = v * r0;
    float c00 = (1.f - r1) * (1.f - r2), c01 = (1.f - r1) * r2;
    float c10 = r1 * (1.f - r2),         c11 = r1 * r2;
    float w8[8] = {va * c00, va * c01, va * c10, va * c11,
                   vb * c00, vb * c01, vb * c10, vb * c11};
    // segmented inclusive scan over lanes (valid because sorted)
#pragma unroll
    for (int s2 = 1; s2 < 64; s2 <<= 1) {
      int cn = __shfl_up(cell, s2);
      bool add = (lane >= s2) && (cn == cell);
#pragma unroll
      for (int j = 0; j < 8; ++j) {
        float x = __shfl_up(w8[j], s2);
        if (add) w8[j] += x;
      }
    }
    int cnext = __shfl_down(cell, 1);
    bool tail = (lane == 63) || (cnext != cell);
    if (tail) {
      atomicAdd(&tile[cell],        w8[0]);
      atomicAdd(&tile[cell + 1],    w8[1]);
      atomicAdd(&tile[cell + 32],   w8[2]);
      atomicAdd(&tile[cell + 33],   w8[3]);
      atomicAdd(&tile[cell + 1024], w8[4]);
      atomicAdd(&tile[cell + 1025], w8[5]);
      atomicAdd(&tile[cell + 1056], w8[6]);
      atomicAdd(&tile[cell + 1057], w8[7]);
    }
  }
  __syncthreads();

  unsigned int cnt = 0;
  float* dst = zout + (size_t)blk * NC_;
#pragma unroll
  for (int i = 0; i < 16; ++i) {
    float4 v = ((const float4*)tile)[t + i * 512];
    cnt += (fabsf(v.x) > 1e-9f) ? 1u : 0u;
    cnt += (fabsf(v.y) > 1e-9f) ? 1u : 0u;
    cnt += (fabsf(v.z) > 1e-9f) ? 1u : 0u;
    cnt += (fabsf(v.w) > 1e-9f) ? 1u : 0u;
    ((float4*)dst)[t + i * 512] = v;
  }
#pragma unroll
  for (int off = 32; off; off >>= 1) cnt += __shfl_down(cnt, off);
  __shared__ unsigned int wc[8];
  if ((t & 63) == 0) wc[t >> 6] = cnt;
  __syncthreads();
  if (t == 0) {
    unsigned int s = 0;
#pragma unroll
    for (int i = 0; i < 8; ++i) s += wc[i];
    atomicAdd(occ, s);
  }
}

// ---- fallback path (small ws): direct final-layout splat ----
__global__ __launch_bounds__(256) void splat_final_kernel(const float* __restrict__ KV,
                                                          const float* __restrict__ orig,
                                                          const float* __restrict__ proj,
                                                          const float* __restrict__ scale,
                                                          const float* __restrict__ shift,
                                                          float* __restrict__ Z,
                                                          float* __restrict__ kacc) {
  const int bh = blockIdx.x >> 7;
  const int n0 = (blockIdx.x & 127) << 6;
  const int b = bh >> 3, h = bh & 7;
  __shared__ float vals[64][65];
  __shared__ int   cellS[64];
  __shared__ float rS[64][4];
  const int t = threadIdx.x;
  const float* KVb = KV + (size_t)b * OC_ * N_;
  const int ch0 = 24 + h * 64;
#pragma unroll
  for (int i = 0; i < 16; ++i) {
    int idx = t + i * 256;
    int f = idx >> 6, p = idx & 63;
    int ch = ch0 + f;
    vals[f][p] = fmaf(KVb[(size_t)ch * N_ + n0 + p], scale[ch], shift[ch]);
  }
  if (t < 64) {
    const int n = n0 + t;
    float pt[3];
#pragma unroll
    for (int k = 0; k < 3; ++k) {
      int ch = h * 3 + k;
      float kr = fmaf(KVb[(size_t)ch * N_ + n], scale[ch], shift[ch]);
      pt[k] = orig[((size_t)b * 3 + k) * N_ + n] + kr;
    }
    float ksum = 0.f, ksq = 0.f;
    int cell = 0;
    float rr[3];
#pragma unroll
    for (int d = 0; d < 3; ++d) {
      const float* pr = proj + (h * 3 + d) * 3;
      float key = pr[0] * pt[0] + pr[1] * pt[1] + pr[2] * pt[2];
      ksum += key; ksq += key * key;
      float lat = tanhf(key);
      float c = (lat + 1.0f) * 15.5f;
      float fl = floorf(c);
      fl = fminf(fmaxf(fl, 0.0f), 30.0f);
      rr[d] = c - fl;
      cell += (int)fl * ((d == 0) ? 1024 : (d == 1) ? 32 : 1);
    }
    cellS[t] = cell;
    rS[t][0] = rr[0]; rS[t][1] = rr[1]; rS[t][2] = rr[2];
#pragma unroll
    for (int off = 32; off; off >>= 1) {
      ksum += __shfl_down(ksum, off);
      ksq  += __shfl_down(ksq, off);
    }
    if (t == 0) { atomicAdd(&kacc[0], ksum); atomicAdd(&kacc[1], ksq); }
  }
  __syncthreads();
  const int w = t >> 6, l = t & 63;
  for (int pi = 0; pi < 16; ++pi) {
    int p = w * 16 + pi;
    int cell = cellS[p];
    float r0 = rS[p][0], r1 = rS[p][1], r2 = rS[p][2];
    float u0 = 1.f - r0, u1 = 1.f - r1, u2 = 1.f - r2;
    float v = vals[l][p];
#pragma unroll
    for (int c = 0; c < 8; ++c) {
      float wt = ((c & 4) ? r0 : u0) * ((c & 2) ? r1 : u1) * ((c & 1) ? r2 : u2);
      int cc = cell + ((c & 4) ? 1024 : 0) + ((c & 2) ? 32 : 0) + (c & 1);
      atomicAdd(Z + (size_t)(bh * 64 + l) * NC_ + cc, v * wt);
    }
  }
}

__global__ __launch_bounds__(256) void count_kernel(const float* __restrict__ Z,
                                                    unsigned int* __restrict__ occ) {
  unsigned int cnt = 0;
  for (long long i = (long long)blockIdx.x * blockDim.x + threadIdx.x; i < ZTOT_;
       i += (long long)gridDim.x * blockDim.x)
    cnt += (fabsf(Z[i]) > 1e-9f) ? 1u : 0u;
#pragma unroll
  for (int off = 32; off; off >>= 1) cnt += __shfl_down(cnt, off);
  __shared__ unsigned int wc[4];
  const int t = threadIdx.x;
  if ((t & 63) == 0) wc[t >> 6] = cnt;
  __syncthreads();
  if (t == 0) atomicAdd(occ, wc[0] + wc[1] + wc[2] + wc[3]);
}

__global__ void finalize_kernel(const unsigned int* __restrict__ occ,
                                const float* __restrict__ kacc,
                                float* __restrict__ tail) {
  float mean = kacc[0] / NKEYS_;
  tail[0] = (float)(*occ) * (1.0f / 2048.0f);
  tail[1] = mean;
  tail[2] = kacc[1] / NKEYS_ - mean * mean;
}

// ============================================================
extern "C" void kernel_launch(void* const* d_in, const int* in_sizes, int n_in,
                              void* d_out, int out_size, void* d_ws, size_t ws_size,
                              hipStream_t stream) {
  const float* X    = (const float*)d_in[0];
  const float* orig = (const float*)d_in[1];
  const float* W    = (const float*)d_in[2];
  const float* kg   = (const float*)d_in[3];
  const float* kb   = (const float*)d_in[4];
  const float* vg   = (const float*)d_in[5];
  const float* vb   = (const float*)d_in[6];
  const float* proj = (const float*)d_in[7];
  float* out = (float*)d_out;

  // ws stats page
  float* P = (float*)d_ws;
  float* ssum  = P;                         // [536]
  float* s2sum = P + 544;                   // [536]
  float* kacc  = P + 1088;                  // [2]
  unsigned int* occ = (unsigned int*)(P + 1090);
  float* scale = P + 1152;                  // [536]
  float* shift = P + 1696;                  // [536]
  char* wsb = (char*)d_ws;

  const size_t need = (size_t)82 << 20;
  if (ws_size >= need) {
    float4* cellr  = (float4*)(wsb + ((size_t)1 << 20));  // 4 MB @1MB
    float4* sorted = (float4*)(wsb + ((size_t)5 << 20));  // 4 MB @5MB
    float*  kv     = (float*)(wsb + ((size_t)9 << 20));   // 67 MB @9MB

    hipMemsetAsync(P, 0, 4368, stream);

    gemm_kernel<<<dim3(N_ / 256, 9, B_), 256, 0, stream>>>(W, X, kv, ssum, s2sum);
    bnfin_kernel<<<3, 256, 0, stream>>>(ssum, s2sum, kg, kb, vg, vb, scale, shift);
    passk_kernel<<<NPTS_ / 256, 256, 0, stream>>>(kv, orig, proj, scale, shift,
                                                  cellr, kacc);
    sortk_kernel<<<32, 1024, 0, stream>>>(cellr, sorted);
    accum_kernel<<<2048, 512, 0, stream>>>(kv, scale, shift, sorted, out, occ);
    finalize_kernel<<<1, 1, 0, stream>>>(occ, kacc, out + ZTOT_);
  } else {
    // fallback: kv in ws, splat straight into d_out final layout
    float* kv = (float*)(wsb + 16384);
    hipMemsetAsync(P, 0, 4368, stream);
    hipMemsetAsync(out, 0, (size_t)ZTOT_ * 4, stream);
    gemm_kernel<<<dim3(N_ / 256, 9, B_), 256, 0, stream>>>(W, X, kv, ssum, s2sum);
    bnfin_kernel<<<3, 256, 0, stream>>>(ssum, s2sum, kg, kb, vg, vb, scale, shift);
    splat_final_kernel<<<B_ * HEADS_ * (N_ / 64), 256, 0, stream>>>(
        kv, orig, proj, scale, shift, out, kacc);
    count_kernel<<<2048, 256, 0, stream>>>(out, occ);
    finalize_kernel<<<1, 1, 0, stream>>>(occ, kacc, out + ZTOT_);
  }
}

// Round 6
// 762.292 us; speedup vs baseline: 1.4417x; 1.1463x over previous
//
#include <hip/hip_runtime.h>
#include <hip/hip_bf16.h>

// ---- problem constants ----
#define B_     4
#define N_     8192
#define MD_    512
#define OC_    536        // HEADS*(FEAT+3)
#define HEADS_ 8
#define FEAT_  64
#define NC_    32768      // 32^3 cells
#define ZTOT_  67108864ll // B*HEADS*FEAT*NC
#define NPTS_  262144     // B*HEADS*N
#define NKEYS_ 786432.0f  // B*HEADS*3*N

// ============================================================
// Kernel 1: GEMM  kv[b][o][n] = sum_m W[o][m] * X[b][m][n]
// + fused per-channel partial sums for BN stats (atomic f32)
// ============================================================
__global__ __launch_bounds__(256) void gemm_kernel(const float* __restrict__ W,
                                                   const float* __restrict__ X,
                                                   float* __restrict__ KV,
                                                   float* __restrict__ ssum,
                                                   float* __restrict__ s2sum) {
  const int n0 = blockIdx.x * 256;
  const int m0 = blockIdx.y * 64;
  const int b  = blockIdx.z;
  __shared__ float Wt[32][68];    // Wt[k][m]
  __shared__ float In[32][260];   // In[k][n]
  const int t  = threadIdx.x;
  const int tx = t & 31;
  const int ty = t >> 5;
  float acc[8][8];
#pragma unroll
  for (int r = 0; r < 8; ++r)
#pragma unroll
    for (int c = 0; c < 8; ++c) acc[r][c] = 0.f;

  const float* Xb = X + (size_t)b * MD_ * N_;
  for (int k0 = 0; k0 < MD_; k0 += 32) {
#pragma unroll
    for (int i = 0; i < 8; ++i) {
      int idx = t + i * 256;
      int m = idx >> 5, k = idx & 31;
      int mm = m0 + m;
      Wt[k][m] = (mm < OC_) ? W[(size_t)mm * MD_ + (k0 + k)] : 0.f;
    }
#pragma unroll
    for (int i = 0; i < 8; ++i) {
      int slot = t + i * 256;
      int k = slot >> 6, n4 = slot & 63;
      float4 v = *(const float4*)(Xb + (size_t)(k0 + k) * N_ + n0 + n4 * 4);
      *(float4*)&In[k][n4 * 4] = v;
    }
    __syncthreads();
#pragma unroll
    for (int k = 0; k < 32; ++k) {
      float a[8], bb[8];
      *(float4*)&a[0]  = *(const float4*)&Wt[k][ty * 8];
      *(float4*)&a[4]  = *(const float4*)&Wt[k][ty * 8 + 4];
      *(float4*)&bb[0] = *(const float4*)&In[k][tx * 4];
      *(float4*)&bb[4] = *(const float4*)&In[k][128 + tx * 4];
#pragma unroll
      for (int r = 0; r < 8; ++r)
#pragma unroll
        for (int c = 0; c < 8; ++c)
          acc[r][c] = fmaf(a[r], bb[c], acc[r][c]);
    }
    __syncthreads();
  }
#pragma unroll
  for (int r = 0; r < 8; ++r) {
    int mm = m0 + ty * 8 + r;
    float s = 0.f, s2 = 0.f;
#pragma unroll
    for (int c = 0; c < 8; ++c) { float v = acc[r][c]; s += v; s2 = fmaf(v, v, s2); }
#pragma unroll
    for (int off = 16; off; off >>= 1) {
      s  += __shfl_down(s, off, 32);
      s2 += __shfl_down(s2, off, 32);
    }
    if (mm < OC_) {
      float* dst = KV + ((size_t)b * OC_ + mm) * N_ + n0;
      *(float4*)(dst + tx * 4)       = *(float4*)&acc[r][0];
      *(float4*)(dst + 128 + tx * 4) = *(float4*)&acc[r][4];
      if (tx == 0) { atomicAdd(&ssum[mm], s); atomicAdd(&s2sum[mm], s2); }
    }
  }
}

// ============================================================
// Kernel 2: finalize BN -> scale/shift per channel
// ============================================================
__global__ __launch_bounds__(256) void bnfin_kernel(const float* __restrict__ ssum,
                                                    const float* __restrict__ s2sum,
                                                    const float* __restrict__ kg,
                                                    const float* __restrict__ kb,
                                                    const float* __restrict__ vg,
                                                    const float* __restrict__ vb,
                                                    float* __restrict__ scale,
                                                    float* __restrict__ shift) {
  const int o = blockIdx.x * 256 + threadIdx.x;
  if (o >= OC_) return;
  const float inv = 1.0f / (B_ * N_);
  float mu  = ssum[o] * inv;
  float var = s2sum[o] * inv - mu * mu;
  float g, be;
  if (o < 24) { g = kg[o]; be = kb[o]; }
  else        { g = vg[o - 24]; be = vb[o - 24]; }
  float sc = g * rsqrtf(var + 1e-5f);
  scale[o] = sc;
  shift[o] = be - mu * sc;
}

// ============================================================
// Kernel 3: per-point keys -> {r0,r1,r2, cell} (16B/point)
//           + keys mean/var partials
// ============================================================
__global__ __launch_bounds__(256) void passk_kernel(const float* __restrict__ KV,
                                                    const float* __restrict__ orig,
                                                    const float* __restrict__ proj,
                                                    const float* __restrict__ scale,
                                                    const float* __restrict__ shift,
                                                    float4* __restrict__ cellr,
                                                    float* __restrict__ kacc) {
  const int p = blockIdx.x * 256 + threadIdx.x;
  const int bh = p >> 13, n = p & (N_ - 1);
  const int b = bh >> 3, h = bh & 7;
  const float* KVb = KV + (size_t)b * OC_ * N_;
  float pt[3];
#pragma unroll
  for (int k = 0; k < 3; ++k) {
    int ch = h * 3 + k;
    float kr = fmaf(KVb[(size_t)ch * N_ + n], scale[ch], shift[ch]);
    pt[k] = orig[((size_t)b * 3 + k) * N_ + n] + kr;
  }
  float ksum = 0.f, ksq = 0.f;
  int cell = 0;
  float rr[3];
#pragma unroll
  for (int d = 0; d < 3; ++d) {
    const float* pr = proj + (h * 3 + d) * 3;
    float key = pr[0] * pt[0] + pr[1] * pt[1] + pr[2] * pt[2];
    ksum += key; ksq += key * key;
    float lat = tanhf(key);
    float c = (lat + 1.0f) * 15.5f;
    float fl = floorf(c);
    fl = fminf(fmaxf(fl, 0.0f), 30.0f);
    rr[d] = c - fl;
    cell += (int)fl * ((d == 0) ? 1024 : (d == 1) ? 32 : 1);
  }
  cellr[p] = make_float4(rr[0], rr[1], rr[2], __int_as_float(cell));
#pragma unroll
  for (int off = 32; off; off >>= 1) {
    ksum += __shfl_down(ksum, off);
    ksq  += __shfl_down(ksq, off);
  }
  if ((threadIdx.x & 63) == 0) {
    atomicAdd(&kacc[0], ksum);
    atomicAdd(&kacc[1], ksq);
  }
}

// ============================================================
// Kernel 3b: per-bh counting sort of points by cell (grouping).
// LDS histogram = 32768 bins (128 KiB), bank-staggered scans.
// Output: sorted[bh][i] = {r0,r1,r2, bitcast(cell | n<<15)}
// ============================================================
__global__ __launch_bounds__(1024, 1) void sortk_kernel(const float4* __restrict__ cellr,
                                                        float4* __restrict__ sorted) {
  const int bh = blockIdx.x;
  __shared__ int hist[NC_];      // 128 KiB
  __shared__ int wsum[16];
  const int t = threadIdx.x;
  for (int i = t; i < NC_; i += 1024) hist[i] = 0;
  __syncthreads();
  const float4* cr = cellr + (size_t)bh * N_;
#pragma unroll
  for (int i = 0; i < 8; ++i) {
    int cell = __float_as_int(cr[t + i * 1024].w);
    atomicAdd(&hist[cell], 1);
  }
  __syncthreads();
  const int base = t * 32;
  int s = 0;
#pragma unroll
  for (int j = 0; j < 32; ++j) s += hist[base + ((j + t) & 31)];
  const int lane = t & 63, wv = t >> 6;
  int sc = s;
#pragma unroll
  for (int off = 1; off < 64; off <<= 1) {
    int x = __shfl_up(sc, off);
    if (lane >= off) sc += x;
  }
  if (lane == 63) wsum[wv] = sc;
  __syncthreads();
  if (t < 16) {
    int x = wsum[t];
    int sc2 = x;
#pragma unroll
    for (int off = 1; off < 16; off <<= 1) {
      int y = __shfl_up(sc2, off);
      if (t >= off) sc2 += y;
    }
    wsum[t] = sc2 - x;    // exclusive wave offset
  }
  __syncthreads();
  int run = sc - s + wsum[wv];   // exclusive start of this thread's chunk
#pragma unroll
  for (int j = 0; j < 32; ++j) {
    int idx = base + ((j + t) & 31);
    int v = hist[idx];
    hist[idx] = run;
    run += v;
  }
  __syncthreads();
  float4* dst = sorted + (size_t)bh * N_;
#pragma unroll
  for (int i = 0; i < 8; ++i) {
    int n = t + i * 1024;
    float4 m = cr[n];
    int cell = __float_as_int(m.w);
    int pos = atomicAdd(&hist[cell], 1);
    m.w = __int_as_float(cell | (n << 15));
    dst[pos] = m;
  }
}

// ============================================================
// Kernel 4: dense accumulate — block = (bh, feat), full 32^3
// grid in 128 KiB LDS. Each THREAD owns 16 consecutive sorted
// entries and merges equal-cell runs in REGISTERS (scalar FMA),
// touching the LDS atomic pipe only once per run.
// ============================================================
__global__ __launch_bounds__(512, 1) void accum_kernel(const float* __restrict__ KV,
                                                       const float* __restrict__ scale,
                                                       const float* __restrict__ shift,
                                                       const float4* __restrict__ sorted,
                                                       float* __restrict__ zout,
                                                       unsigned int* __restrict__ occ) {
  const int blk = blockIdx.x;       // bh*64 + f
  const int f   = blk & 63;
  const int bh  = blk >> 6;
  const int b = bh >> 3, h = bh & 7;
  __shared__ float tile[NC_];       // 128 KiB
  const int t = threadIdx.x;
#pragma unroll
  for (int i = 0; i < 16; ++i)
    ((float4*)tile)[t + i * 512] = make_float4(0.f, 0.f, 0.f, 0.f);
  __syncthreads();

  const int ch = 24 + h * 64 + f;
  const float sc = scale[ch], sh = shift[ch];
  const float* kvrow = KV + ((size_t)b * OC_ + ch) * N_;
  const float4* sp = sorted + (size_t)bh * N_;
  const int base = t * 16;

  // prefetch 16 entries + 16 kv gathers (all independent loads)
  float4 e[16];
#pragma unroll
  for (int i = 0; i < 16; ++i) e[i] = sp[base + i];
  float kvv[16];
#pragma unroll
  for (int i = 0; i < 16; ++i)
    kvv[i] = kvrow[((unsigned)__float_as_int(e[i].w)) >> 15];

#define FLUSH()                                                     \
  {                                                                 \
    atomicAdd(&tile[cur],        m0_);                              \
    atomicAdd(&tile[cur + 1],    m1_);                              \
    atomicAdd(&tile[cur + 32],   m2_);                              \
    atomicAdd(&tile[cur + 33],   m3_);                              \
    atomicAdd(&tile[cur + 1024], m4_);                              \
    atomicAdd(&tile[cur + 1025], m5_);                              \
    atomicAdd(&tile[cur + 1056], m6_);                              \
    atomicAdd(&tile[cur + 1057], m7_);                              \
  }

  float m0_ = 0.f, m1_ = 0.f, m2_ = 0.f, m3_ = 0.f;
  float m4_ = 0.f, m5_ = 0.f, m6_ = 0.f, m7_ = 0.f;
  int cur = __float_as_int(e[0].w) & 32767;
#pragma unroll
  for (int i = 0; i < 16; ++i) {
    int cell = __float_as_int(e[i].w) & 32767;
    if (cell != cur) {
      FLUSH();
      m0_ = m1_ = m2_ = m3_ = m4_ = m5_ = m6_ = m7_ = 0.f;
      cur = cell;
    }
    float v  = fmaf(kvv[i], sc, sh);
    float r0 = e[i].x, r1 = e[i].y, r2 = e[i].z;
    float va = v * (1.f - r0), vb = v * r0;
    float c00 = (1.f - r1) * (1.f - r2), c01 = (1.f - r1) * r2;
    float c10 = r1 * (1.f - r2),         c11 = r1 * r2;
    m0_ = fmaf(va, c00, m0_); m1_ = fmaf(va, c01, m1_);
    m2_ = fmaf(va, c10, m2_); m3_ = fmaf(va, c11, m3_);
    m4_ = fmaf(vb, c00, m4_); m5_ = fmaf(vb, c01, m5_);
    m6_ = fmaf(vb, c10, m6_); m7_ = fmaf(vb, c11, m7_);
  }
  FLUSH();
#undef FLUSH
  __syncthreads();

  unsigned int cnt = 0;
  float* dst = zout + (size_t)blk * NC_;
#pragma unroll
  for (int i = 0; i < 16; ++i) {
    float4 v = ((const float4*)tile)[t + i * 512];
    cnt += (fabsf(v.x) > 1e-9f) ? 1u : 0u;
    cnt += (fabsf(v.y) > 1e-9f) ? 1u : 0u;
    cnt += (fabsf(v.z) > 1e-9f) ? 1u : 0u;
    cnt += (fabsf(v.w) > 1e-9f) ? 1u : 0u;
    ((float4*)dst)[t + i * 512] = v;
  }
#pragma unroll
  for (int off = 32; off; off >>= 1) cnt += __shfl_down(cnt, off);
  __shared__ unsigned int wc[8];
  if ((t & 63) == 0) wc[t >> 6] = cnt;
  __syncthreads();
  if (t == 0) {
    unsigned int s = 0;
#pragma unroll
    for (int i = 0; i < 8; ++i) s += wc[i];
    atomicAdd(occ, s);
  }
}

// ---- fallback path (small ws): direct final-layout splat ----
__global__ __launch_bounds__(256) void splat_final_kernel(const float* __restrict__ KV,
                                                          const float* __restrict__ orig,
                                                          const float* __restrict__ proj,
                                                          const float* __restrict__ scale,
                                                          const float* __restrict__ shift,
                                                          float* __restrict__ Z,
                                                          float* __restrict__ kacc) {
  const int bh = blockIdx.x >> 7;
  const int n0 = (blockIdx.x & 127) << 6;
  const int b = bh >> 3, h = bh & 7;
  __shared__ float vals[64][65];
  __shared__ int   cellS[64];
  __shared__ float rS[64][4];
  const int t = threadIdx.x;
  const float* KVb = KV + (size_t)b * OC_ * N_;
  const int ch0 = 24 + h * 64;
#pragma unroll
  for (int i = 0; i < 16; ++i) {
    int idx = t + i * 256;
    int f = idx >> 6, p = idx & 63;
    int ch = ch0 + f;
    vals[f][p] = fmaf(KVb[(size_t)ch * N_ + n0 + p], scale[ch], shift[ch]);
  }
  if (t < 64) {
    const int n = n0 + t;
    float pt[3];
#pragma unroll
    for (int k = 0; k < 3; ++k) {
      int ch = h * 3 + k;
      float kr = fmaf(KVb[(size_t)ch * N_ + n], scale[ch], shift[ch]);
      pt[k] = orig[((size_t)b * 3 + k) * N_ + n] + kr;
    }
    float ksum = 0.f, ksq = 0.f;
    int cell = 0;
    float rr[3];
#pragma unroll
    for (int d = 0; d < 3; ++d) {
      const float* pr = proj + (h * 3 + d) * 3;
      float key = pr[0] * pt[0] + pr[1] * pt[1] + pr[2] * pt[2];
      ksum += key; ksq += key * key;
      float lat = tanhf(key);
      float c = (lat + 1.0f) * 15.5f;
      float fl = floorf(c);
      fl = fminf(fmaxf(fl, 0.0f), 30.0f);
      rr[d] = c - fl;
      cell += (int)fl * ((d == 0) ? 1024 : (d == 1) ? 32 : 1);
    }
    cellS[t] = cell;
    rS[t][0] = rr[0]; rS[t][1] = rr[1]; rS[t][2] = rr[2];
#pragma unroll
    for (int off = 32; off; off >>= 1) {
      ksum += __shfl_down(ksum, off);
      ksq  += __shfl_down(ksq, off);
    }
    if (t == 0) { atomicAdd(&kacc[0], ksum); atomicAdd(&kacc[1], ksq); }
  }
  __syncthreads();
  const int w = t >> 6, l = t & 63;
  for (int pi = 0; pi < 16; ++pi) {
    int p = w * 16 + pi;
    int cell = cellS[p];
    float r0 = rS[p][0], r1 = rS[p][1], r2 = rS[p][2];
    float u0 = 1.f - r0, u1 = 1.f - r1, u2 = 1.f - r2;
    float v = vals[l][p];
#pragma unroll
    for (int c = 0; c < 8; ++c) {
      float wt = ((c & 4) ? r0 : u0) * ((c & 2) ? r1 : u1) * ((c & 1) ? r2 : u2);
      int cc = cell + ((c & 4) ? 1024 : 0) + ((c & 2) ? 32 : 0) + (c & 1);
      atomicAdd(Z + (size_t)(bh * 64 + l) * NC_ + cc, v * wt);
    }
  }
}

__global__ __launch_bounds__(256) void count_kernel(const float* __restrict__ Z,
                                                    unsigned int* __restrict__ occ) {
  unsigned int cnt = 0;
  for (long long i = (long long)blockIdx.x * blockDim.x + threadIdx.x; i < ZTOT_;
       i += (long long)gridDim.x * blockDim.x)
    cnt += (fabsf(Z[i]) > 1e-9f) ? 1u : 0u;
#pragma unroll
  for (int off = 32; off; off >>= 1) cnt += __shfl_down(cnt, off);
  __shared__ unsigned int wc[4];
  const int t = threadIdx.x;
  if ((t & 63) == 0) wc[t >> 6] = cnt;
  __syncthreads();
  if (t == 0) atomicAdd(occ, wc[0] + wc[1] + wc[2] + wc[3]);
}

__global__ void finalize_kernel(const unsigned int* __restrict__ occ,
                                const float* __restrict__ kacc,
                                float* __restrict__ tail) {
  float mean = kacc[0] / NKEYS_;
  tail[0] = (float)(*occ) * (1.0f / 2048.0f);
  tail[1] = mean;
  tail[2] = kacc[1] / NKEYS_ - mean * mean;
}

// ============================================================
extern "C" void kernel_launch(void* const* d_in, const int* in_sizes, int n_in,
                              void* d_out, int out_size, void* d_ws, size_t ws_size,
                              hipStream_t stream) {
  const float* X    = (const float*)d_in[0];
  const float* orig = (const float*)d_in[1];
  const float* W    = (const float*)d_in[2];
  const float* kg   = (const float*)d_in[3];
  const float* kb   = (const float*)d_in[4];
  const float* vg   = (const float*)d_in[5];
  const float* vb   = (const float*)d_in[6];
  const float* proj = (const float*)d_in[7];
  float* out = (float*)d_out;

  // ws stats page
  float* P = (float*)d_ws;
  float* ssum  = P;                         // [536]
  float* s2sum = P + 544;                   // [536]
  float* kacc  = P + 1088;                  // [2]
  unsigned int* occ = (unsigned int*)(P + 1090);
  float* scale = P + 1152;                  // [536]
  float* shift = P + 1696;                  // [536]
  char* wsb = (char*)d_ws;

  const size_t need = (size_t)82 << 20;
  if (ws_size >= need) {
    float4* cellr  = (float4*)(wsb + ((size_t)1 << 20));  // 4 MB @1MB
    float4* sorted = (float4*)(wsb + ((size_t)5 << 20));  // 4 MB @5MB
    float*  kv     = (float*)(wsb + ((size_t)9 << 20));   // 67 MB @9MB

    hipMemsetAsync(P, 0, 4368, stream);

    gemm_kernel<<<dim3(N_ / 256, 9, B_), 256, 0, stream>>>(W, X, kv, ssum, s2sum);
    bnfin_kernel<<<3, 256, 0, stream>>>(ssum, s2sum, kg, kb, vg, vb, scale, shift);
    passk_kernel<<<NPTS_ / 256, 256, 0, stream>>>(kv, orig, proj, scale, shift,
                                                  cellr, kacc);
    sortk_kernel<<<32, 1024, 0, stream>>>(cellr, sorted);
    accum_kernel<<<2048, 512, 0, stream>>>(kv, scale, shift, sorted, out, occ);
    finalize_kernel<<<1, 1, 0, stream>>>(occ, kacc, out + ZTOT_);
  } else {
    // fallback: kv in ws, splat straight into d_out final layout
    float* kv = (float*)(wsb + 16384);
    hipMemsetAsync(P, 0, 4368, stream);
    hipMemsetAsync(out, 0, (size_t)ZTOT_ * 4, stream);
    gemm_kernel<<<dim3(N_ / 256, 9, B_), 256, 0, stream>>>(W, X, kv, ssum, s2sum);
    bnfin_kernel<<<3, 256, 0, stream>>>(ssum, s2sum, kg, kb, vg, vb, scale, shift);
    splat_final_kernel<<<B_ * HEADS_ * (N_ / 64), 256, 0, stream>>>(
        kv, orig, proj, scale, shift, out, kacc);
    count_kernel<<<2048, 256, 0, stream>>>(out, occ);
    finalize_kernel<<<1, 1, 0, stream>>>(occ, kacc, out + ZTOT_);
  }
}